// Round 2
// baseline (607.512 us; speedup 1.0000x reference)
//
#include <hip/hip_runtime.h>

// SpaAggregator: out[b] = (mean_k id2feat[idx[b,k]]) @ W + bias
// B=16384, K=32, N=1e6, F=128, E=128. float32 in/out, int32 indices.
//
// mean commutes with the linear map: gather-average first (256 MB random
// 512B-row reads, memory-bound), then a tiny per-block GEMM from LDS.
// Block = 256 threads handles 16 batch rows:
//   phase 1: stage idx tile + W -> fp32 LDS (interleaved layout so phase-3
//            ds_read_b128 is only 2-way bank aliased = free)
//   phase 2: gather-average 16 rows x 32 neighbors; 16 lanes x 32B cover one
//            512B table row contiguously
//   phase 3: per-thread 1x8 output tile GEMM from LDS, fp32 store.

#define BATCH 16384
#define KNB   32
#define FDIM  128
#define EDIM  128
#define ROWS_PER_BLOCK 16
#define IDX_PITCH 33   // pad: banks differ across lb for sIdx reads
#define A_PITCH  132   // pad: kills 4-way conflict on phase-3 broadcast reads

__global__ __launch_bounds__(256, 2)
void spa_agg_kernel(const float* __restrict__ id2feat,
                    const float* __restrict__ weight,
                    const float* __restrict__ bias,
                    const int* __restrict__ neigh_idx,
                    float* __restrict__ out) {
    __shared__ float sW[FDIM * EDIM];                  // 64 KB, interleaved
    __shared__ float sA[ROWS_PER_BLOCK * A_PITCH];     // ~8.25 KB
    __shared__ int   sIdx[ROWS_PER_BLOCK * IDX_PITCH]; // ~2.1 KB

    const int tid = threadIdx.x;
    const int lb  = tid >> 4;   // 0..15 : local batch row
    const int fg  = tid & 15;   // 0..15 : 8-wide feature/embed chunk
    const int b0  = blockIdx.x * ROWS_PER_BLOCK;

    // ---- phase 1a: stage neighbor indices ----
    {
        const int base = b0 * KNB;
        for (int i = tid; i < ROWS_PER_BLOCK * KNB; i += 256) {
            int r = i >> 5, c = i & 31;  // KNB = 32
            sIdx[r * IDX_PITCH + c] = neigh_idx[base + i];
        }
    }
    // ---- phase 1b: W -> LDS, interleaved layout ----
    // e = eg*8 + half*4 + j  ->  sW[f*128 + half*64 + eg*4 + j]
    // each source float4 (e4 = e/4) maps to a contiguous dest float4:
    //   dst = f*128 + (e4&1)*64 + (e4>>1)*4
    {
        for (int i = tid; i < (FDIM * EDIM) / 4; i += 256) {
            int f = i >> 5, e4 = i & 31;
            const float4 w = *(const float4*)(weight + (size_t)f * EDIM + e4 * 4);
            *(float4*)&sW[f * 128 + (e4 & 1) * 64 + (e4 >> 1) * 4] = w;
        }
    }
    __syncthreads();

    // ---- phase 2: gather + average ----
    // thread (lb, fg) accumulates features [fg*8, fg*8+8) of local row lb.
    // 16 consecutive lanes read one 512B table row contiguously (32B/lane).
    {
        float acc[8];
        #pragma unroll
        for (int j = 0; j < 8; ++j) acc[j] = 0.f;
        const int* ip = &sIdx[lb * IDX_PITCH];
        #pragma unroll 8
        for (int k = 0; k < KNB; ++k) {
            const int row = ip[k];
            const float4* rp = (const float4*)(id2feat + (size_t)row * FDIM + fg * 8);
            const float4 r0 = rp[0];
            const float4 r1 = rp[1];
            acc[0] += r0.x; acc[1] += r0.y; acc[2] += r0.z; acc[3] += r0.w;
            acc[4] += r1.x; acc[5] += r1.y; acc[6] += r1.z; acc[7] += r1.w;
        }
        float* ap = &sA[lb * A_PITCH + fg * 8];
        #pragma unroll
        for (int j = 0; j < 8; ++j) ap[j] = acc[j] * (1.f / 32.f);
    }
    __syncthreads();

    // ---- phase 3: out[b0+lb][e0..e0+8) = sA[lb] . sW[:, e0..e0+8) + bias ----
    {
        const int e0 = fg * 8;
        float acc[8];
        #pragma unroll
        for (int j = 0; j < 8; ++j) acc[j] = bias[e0 + j];
        const float* arow = &sA[lb * A_PITCH];
        #pragma unroll 4
        for (int f = 0; f < FDIM; ++f) {
            const float a   = arow[f];                             // LDS broadcast
            const float4 w0 = *(const float4*)&sW[f * 128 + fg * 4];
            const float4 w1 = *(const float4*)&sW[f * 128 + 64 + fg * 4];
            acc[0] += a * w0.x; acc[1] += a * w0.y;
            acc[2] += a * w0.z; acc[3] += a * w0.w;
            acc[4] += a * w1.x; acc[5] += a * w1.y;
            acc[6] += a * w1.z; acc[7] += a * w1.w;
        }
        float* op = out + (size_t)(b0 + lb) * EDIM + e0;
        *(float4*)op       = make_float4(acc[0], acc[1], acc[2], acc[3]);
        *(float4*)(op + 4) = make_float4(acc[4], acc[5], acc[6], acc[7]);
    }
}

extern "C" void kernel_launch(void* const* d_in, const int* in_sizes, int n_in,
                              void* d_out, int out_size, void* d_ws, size_t ws_size,
                              hipStream_t stream) {
    const float* id2feat = (const float*)d_in[0];  // [N, F] fp32
    const float* weight  = (const float*)d_in[1];  // [F, E] fp32
    const float* bias    = (const float*)d_in[2];  // [E]    fp32
    const int*   neigh   = (const int*)d_in[3];    // [B, K] int32
    float*       outp    = (float*)d_out;          // [B, E] fp32

    dim3 grid(BATCH / ROWS_PER_BLOCK);  // 1024
    dim3 block(256);
    spa_agg_kernel<<<grid, block, 0, stream>>>(id2feat, weight, bias, neigh, outp);
}